// Round 1
// baseline (361.034 us; speedup 1.0000x reference)
//
#include <hip/hip_runtime.h>
#include <math.h>

// Problem constants (B=2, T=8, H=W=56, C=128, heads=8, hd=16, WS=7, nh=nw=8)
constexpr int H_   = 56;
constexpr int HW_  = 56 * 56;          // 3136
constexpr int NPIX = 8 * HW_;          // 25088 (per batch)
constexpr int SLAB = 128 * HW_ * 16;   // 6422528 floats per q/k/v buffer

// ---------------------------------------------------------------------------
// GEMM: Y[M x 128] = X[M x 128] @ W[128 x 128]^T (+epilogue). 128x128 tile,
// KT=32, LDS stored transposed [c][row] so fragment reads are float4.
// MODE 0: qkv (blockIdx.y = which of q/k/v; 128 ocs = 8 heads x 16), epilogue
//         l2-normalizes q/k per (pixel, head) via shfl butterflies and
//         scatters to (BT, HW, 16) layout.
// MODE 1: proj (adds bias, writes [M x 128] row-major; in-place-safe since a
//         block reads only its own 128 rows before writing them).
// ---------------------------------------------------------------------------
template <int MODE>
__global__ __launch_bounds__(256, 3) void gemm128(
    const float* X, const float* __restrict__ Wt, const float* __restrict__ bias,
    float* __restrict__ Yq, float* __restrict__ Yk, float* __restrict__ Yv,
    float* Yout)
{
  __shared__ float xT[32][132];
  __shared__ float wT[32][132];
  const int tid = threadIdx.x;
  const int tx = tid & 15, ty = tid >> 4;
  const int mbase = blockIdx.x * 128;
  const int nt = (MODE == 0) ? (int)blockIdx.y : 0;
  const float* Wp = Wt + (size_t)nt * (128 * 128);

  float acc[8][8];
#pragma unroll
  for (int i = 0; i < 8; ++i)
#pragma unroll
    for (int j = 0; j < 8; ++j) acc[i][j] = 0.f;

  const int srow = tid >> 3;          // 0..31: row within staging pass
  const int scol = (tid & 7) * 4;     // 0,4,..,28: c-offset within K-tile

  for (int kt = 0; kt < 4; ++kt) {
    if (kt) __syncthreads();
#pragma unroll
    for (int p = 0; p < 4; ++p) {
      int r = p * 32 + srow;
      float4 vx = *(const float4*)&X [(size_t)(mbase + r) * 128 + kt * 32 + scol];
      float4 vw = *(const float4*)&Wp[(size_t)r * 128 + kt * 32 + scol];
      xT[scol + 0][r] = vx.x; xT[scol + 1][r] = vx.y; xT[scol + 2][r] = vx.z; xT[scol + 3][r] = vx.w;
      wT[scol + 0][r] = vw.x; wT[scol + 1][r] = vw.y; wT[scol + 2][r] = vw.z; wT[scol + 3][r] = vw.w;
    }
    __syncthreads();
#pragma unroll 4
    for (int c = 0; c < 32; ++c) {
      float4 a0 = *(const float4*)&xT[c][tx * 4];
      float4 a1 = *(const float4*)&xT[c][64 + tx * 4];
      float4 b0 = *(const float4*)&wT[c][ty * 4];
      float4 b1 = *(const float4*)&wT[c][64 + ty * 4];
      float a[8] = {a0.x, a0.y, a0.z, a0.w, a1.x, a1.y, a1.z, a1.w};
      float b[8] = {b0.x, b0.y, b0.z, b0.w, b1.x, b1.y, b1.z, b1.w};
#pragma unroll
      for (int i = 0; i < 8; ++i)
#pragma unroll
        for (int j = 0; j < 8; ++j) acc[i][j] += a[i] * b[j];
    }
  }

  if (MODE == 0) {
    // thread owns channels cq..cq+3 of head hq (ocs ty*4..) and head hq+4 (ocs 64+ty*4..)
    const int hq = ty >> 2;
    const int cq = (ty & 3) * 4;
    float* Ybase = (nt == 0) ? Yq : ((nt == 1) ? Yk : Yv);
#pragma unroll
    for (int i = 0; i < 8; ++i) {
      int gpix = mbase + ((i < 4) ? (tx * 4 + i) : (64 + tx * 4 + (i - 4)));
      int b = gpix / NPIX;
      int rem = gpix - b * NPIX;
      int t = rem / HW_;
      int s = rem - t * HW_;
      float s0 = acc[i][0]*acc[i][0] + acc[i][1]*acc[i][1] + acc[i][2]*acc[i][2] + acc[i][3]*acc[i][3];
      float s1 = acc[i][4]*acc[i][4] + acc[i][5]*acc[i][5] + acc[i][6]*acc[i][6] + acc[i][7]*acc[i][7];
      // sum the 4 threads (ty, ty^1, ty^2, ty^3) that hold this head's 16 channels
      s0 += __shfl_xor(s0, 16); s0 += __shfl_xor(s0, 32);
      s1 += __shfl_xor(s1, 16); s1 += __shfl_xor(s1, 32);
      float r0 = 1.f, r1 = 1.f;
      if (nt < 2) {  // q and k get l2-normalized
        r0 = 1.f / fmaxf(sqrtf(s0), 1e-12f);
        r1 = 1.f / fmaxf(sqrtf(s1), 1e-12f);
      }
      int bt0 = (b * 8 + hq) * 8 + t;
      int bt1 = (b * 8 + hq + 4) * 8 + t;
      float* d0 = Ybase + ((size_t)bt0 * HW_ + s) * 16 + cq;
      float* d1 = Ybase + ((size_t)bt1 * HW_ + s) * 16 + cq;
      *(float4*)d0 = make_float4(acc[i][0]*r0, acc[i][1]*r0, acc[i][2]*r0, acc[i][3]*r0);
      *(float4*)d1 = make_float4(acc[i][4]*r1, acc[i][5]*r1, acc[i][6]*r1, acc[i][7]*r1);
    }
  } else {
    float4 bb0 = *(const float4*)&bias[ty * 4];
    float4 bb1 = *(const float4*)&bias[64 + ty * 4];
#pragma unroll
    for (int i = 0; i < 8; ++i) {
      int gpix = mbase + ((i < 4) ? (tx * 4 + i) : (64 + tx * 4 + (i - 4)));
      float* dst = Yout + (size_t)gpix * 128;
      *(float4*)&dst[ty * 4]      = make_float4(acc[i][0]+bb0.x, acc[i][1]+bb0.y, acc[i][2]+bb0.z, acc[i][3]+bb0.w);
      *(float4*)&dst[64 + ty * 4] = make_float4(acc[i][4]+bb1.x, acc[i][5]+bb1.y, acc[i][6]+bb1.z, acc[i][7]+bb1.w);
    }
  }
}

// ---------------------------------------------------------------------------
// Fused window attention: one 64-thread block per window (gwin = (bt*8+wy)*8+wx).
// Window pixel i=(a,b2): h = a*8+wy, w = b2*8+wx (dilated windows, per torch
// reshape). Computes corr(qp, kp[t+1]) for 49 displacements on the fly, then
// two attention passes (motion gram over 49 corr channels, appearance gram
// over 16 qw channels) with a streaming softmax. Softmax shift uses the
// Cauchy-Schwarz bound m_i = sqrt(l_ii * max_j l_jj) >= rowmax (exact shift-
// invariance; Delta <= maxdiag/4 ~ 15, so exp stays in normal fp32 range).
// Output written directly in (B, N, C) "mid" layout.
// ---------------------------------------------------------------------------
__global__ __launch_bounds__(64) void attn_win(
    const float* __restrict__ qn, const float* __restrict__ kn, const float* __restrict__ vv,
    const float* __restrict__ pos1, const float* __restrict__ pos2,
    float* __restrict__ mid)
{
  __shared__ float cw[49][52];   // corr + pos1, cols 49..51 zero-padded
  __shared__ float qp[49][20];   // q window (later qw = qp + pos2)
  __shared__ float vs_[49][16];  // v window
  const int lane = threadIdx.x;
  const int gwin = blockIdx.x;
  const int bt = gwin >> 6;
  const int wy = (gwin >> 3) & 7;
  const int wx = gwin & 7;
  const int t = bt & 7;
  const int btk = bt - t + ((t < 7) ? (t + 1) : 7);   // k shifted one frame fwd (clamped)
  const float* qb = qn + (size_t)bt  * (HW_ * 16);
  const float* kb = kn + (size_t)btk * (HW_ * 16);
  const float* vb = vv + (size_t)bt  * (HW_ * 16);

  // P0: load q window and v window (49 x 16 each)
#pragma unroll 1
  for (int f = lane; f < 196; f += 64) {
    int i = f >> 2, c4 = (f & 3) * 4;
    int hh = (i / 7) * 8 + wy, ww = (i % 7) * 8 + wx;
    size_t off = (size_t)(hh * 56 + ww) * 16 + c4;
    *(float4*)&qp[i][c4]  = *(const float4*)&qb[off];
    *(float4*)&vs_[i][c4] = *(const float4*)&vb[off];
  }
  __syncthreads();

  // P1: correlation (49 pixels x 49 displacements) + pos1
#pragma unroll 1
  for (int e = lane; e < 2401; e += 64) {
    int i = e / 49;
    int d = e - i * 49;
    int du = d / 7, dv = d - du * 7;
    int hh = (i / 7) * 8 + wy + du - 3;
    int ww = (i % 7) * 8 + wx + dv - 3;
    float val = 0.f;
    if ((unsigned)hh < 56u && (unsigned)ww < 56u) {
      const float4* kv = (const float4*)&kb[(size_t)(hh * 56 + ww) * 16];
      float4 k0 = kv[0], k1 = kv[1], k2 = kv[2], k3 = kv[3];
      const float* q = qp[i];
      val = q[0]*k0.x + q[1]*k0.y + q[2]*k0.z + q[3]*k0.w
          + q[4]*k1.x + q[5]*k1.y + q[6]*k1.z + q[7]*k1.w
          + q[8]*k2.x + q[9]*k2.y + q[10]*k2.z + q[11]*k2.w
          + q[12]*k3.x + q[13]*k3.y + q[14]*k3.z + q[15]*k3.w;
    }
    cw[i][d] = val + pos1[e];
  }
  if (lane < 49) { cw[lane][49] = 0.f; cw[lane][50] = 0.f; cw[lane][51] = 0.f; }
  __syncthreads();

  const int il = (lane < 49) ? lane : 48;  // lanes 49..63 shadow row 48 (writes guarded)

  // qw = qp + pos2 (in place; raw qp no longer needed after P1)
#pragma unroll 1
  for (int f = lane; f < 196; f += 64) {
    int i = f >> 2, c4 = (f & 3) * 4;
    float4 cur = *(const float4*)&qp[i][c4];
    float4 p2  = *(const float4*)&pos2[i * 16 + c4];
    cur.x += p2.x; cur.y += p2.y; cur.z += p2.z; cur.w += p2.w;
    *(float4*)&qp[i][c4] = cur;
  }

  // ---- motion attention: row il of softmax(cw @ cw^T) @ v ----
  float4 cr[13];
#pragma unroll
  for (int d4 = 0; d4 < 13; ++d4) cr[d4] = *(const float4*)&cw[il][d4 * 4];
  float dii = 0.f;
#pragma unroll
  for (int d4 = 0; d4 < 13; ++d4)
    dii += cr[d4].x*cr[d4].x + cr[d4].y*cr[d4].y + cr[d4].z*cr[d4].z + cr[d4].w*cr[d4].w;
  float md = dii;
#pragma unroll
  for (int o = 32; o >= 1; o >>= 1) md = fmaxf(md, __shfl_xor(md, o));
  const float mi = sqrtf(dii * md);

  float ssum = 0.f;
  float acc[16];
#pragma unroll
  for (int c = 0; c < 16; ++c) acc[c] = 0.f;
#pragma unroll 2
  for (int j = 0; j < 49; ++j) {
    float d0 = 0.f, d1 = 0.f, d2 = 0.f, d3 = 0.f;
#pragma unroll
    for (int d4 = 0; d4 < 13; ++d4) {
      float4 b4 = *(const float4*)&cw[j][d4 * 4];   // uniform addr -> LDS broadcast
      d0 += cr[d4].x * b4.x; d1 += cr[d4].y * b4.y;
      d2 += cr[d4].z * b4.z; d3 += cr[d4].w * b4.w;
    }
    float p = __expf((d0 + d1) + (d2 + d3) - mi);
    ssum += p;
    const float4* vr = (const float4*)&vs_[j][0];
    float4 v0 = vr[0], v1 = vr[1], v2 = vr[2], v3 = vr[3];
    acc[0]  += p*v0.x; acc[1]  += p*v0.y; acc[2]  += p*v0.z; acc[3]  += p*v0.w;
    acc[4]  += p*v1.x; acc[5]  += p*v1.y; acc[6]  += p*v1.z; acc[7]  += p*v1.w;
    acc[8]  += p*v2.x; acc[9]  += p*v2.y; acc[10] += p*v2.z; acc[11] += p*v2.w;
    acc[12] += p*v3.x; acc[13] += p*v3.y; acc[14] += p*v3.z; acc[15] += p*v3.w;
  }
  float mo[16];
  {
    float inv = 0.5f / ssum;
#pragma unroll
    for (int c = 0; c < 16; ++c) mo[c] = acc[c] * inv;
  }
  __syncthreads();  // qw updates visible to all lanes

  // ---- appearance attention: row il of softmax(qw @ qw^T) @ v ----
  float4 qa0 = *(const float4*)&qp[il][0];
  float4 qa1 = *(const float4*)&qp[il][4];
  float4 qa2 = *(const float4*)&qp[il][8];
  float4 qa3 = *(const float4*)&qp[il][12];
  float dia = qa0.x*qa0.x+qa0.y*qa0.y+qa0.z*qa0.z+qa0.w*qa0.w
            + qa1.x*qa1.x+qa1.y*qa1.y+qa1.z*qa1.z+qa1.w*qa1.w
            + qa2.x*qa2.x+qa2.y*qa2.y+qa2.z*qa2.z+qa2.w*qa2.w
            + qa3.x*qa3.x+qa3.y*qa3.y+qa3.z*qa3.z+qa3.w*qa3.w;
  float mda = dia;
#pragma unroll
  for (int o = 32; o >= 1; o >>= 1) mda = fmaxf(mda, __shfl_xor(mda, o));
  const float ma = sqrtf(dia * mda);

  ssum = 0.f;
#pragma unroll
  for (int c = 0; c < 16; ++c) acc[c] = 0.f;
#pragma unroll 2
  for (int j = 0; j < 49; ++j) {
    const float4* qr = (const float4*)&qp[j][0];
    float4 b0 = qr[0], b1 = qr[1], b2 = qr[2], b3 = qr[3];
    float l = qa0.x*b0.x + qa0.y*b0.y + qa0.z*b0.z + qa0.w*b0.w
            + qa1.x*b1.x + qa1.y*b1.y + qa1.z*b1.z + qa1.w*b1.w
            + qa2.x*b2.x + qa2.y*b2.y + qa2.z*b2.z + qa2.w*b2.w
            + qa3.x*b3.x + qa3.y*b3.y + qa3.z*b3.z + qa3.w*b3.w;
    float p = __expf(l - ma);
    ssum += p;
    const float4* vr = (const float4*)&vs_[j][0];
    float4 v0 = vr[0], v1 = vr[1], v2 = vr[2], v3 = vr[3];
    acc[0]  += p*v0.x; acc[1]  += p*v0.y; acc[2]  += p*v0.z; acc[3]  += p*v0.w;
    acc[4]  += p*v1.x; acc[5]  += p*v1.y; acc[6]  += p*v1.z; acc[7]  += p*v1.w;
    acc[8]  += p*v2.x; acc[9]  += p*v2.y; acc[10] += p*v2.z; acc[11] += p*v2.w;
    acc[12] += p*v3.x; acc[13] += p*v3.y; acc[14] += p*v3.z; acc[15] += p*v3.w;
  }

  if (lane < 49) {
    float inva = 0.5f / ssum;
    int b = bt >> 6, e = (bt >> 3) & 7, tt = bt & 7;
    int hh = (il / 7) * 8 + wy, ww = (il % 7) * 8 + wx;
    float* dst = mid + ((size_t)(b * NPIX + tt * HW_ + hh * 56 + ww)) * 128 + e * 16;
    float r[16];
#pragma unroll
    for (int c = 0; c < 16; ++c) r[c] = mo[c] + acc[c] * inva;
    *(float4*)&dst[0]  = make_float4(r[0],  r[1],  r[2],  r[3]);
    *(float4*)&dst[4]  = make_float4(r[4],  r[5],  r[6],  r[7]);
    *(float4*)&dst[8]  = make_float4(r[8],  r[9],  r[10], r[11]);
    *(float4*)&dst[12] = make_float4(r[12], r[13], r[14], r[15]);
  }
}

// ---------------------------------------------------------------------------
extern "C" void kernel_launch(void* const* d_in, const int* in_sizes, int n_in,
                              void* d_out, int out_size, void* d_ws, size_t ws_size,
                              hipStream_t stream) {
  (void)in_sizes; (void)n_in; (void)out_size; (void)ws_size;
  const float* x      = (const float*)d_in[0];   // (2, 25088, 128)
  const float* qkv_w  = (const float*)d_in[1];   // (384, 128)
  const float* proj_w = (const float*)d_in[2];   // (128, 128)
  const float* proj_b = (const float*)d_in[3];   // (128,)
  const float* pos1   = (const float*)d_in[4];   // (1, 49, 49)
  const float* pos2   = (const float*)d_in[5];   // (1, 49, 16)
  float* out = (float*)d_out;                    // (2, 25088, 128)

  float* qn = (float*)d_ws;        // (BT=128, HW=3136, 16) l2-normalized q
  float* kc = qn + SLAB;           // normalized k (natural t; shift applied at read)
  float* vv = kc + SLAB;           // v                            (77 MB total)

  // K1: QKV GEMM + per-head l2norm + scatter
  gemm128<0><<<dim3(392, 3), 256, 0, stream>>>(x, qkv_w, nullptr, qn, kc, vv, nullptr);
  // K2: fused correlation + dual window attention -> mid (in d_out)
  attn_win<<<dim3(8192), 64, 0, stream>>>(qn, kc, vv, pos1, pos2, out);
  // K3: output projection, in-place on d_out (row-disjoint blocks)
  gemm128<1><<<dim3(392), 256, 0, stream>>>(out, proj_w, proj_b, nullptr, nullptr, nullptr, out);
}

// Round 2
// 298.891 us; speedup vs baseline: 1.2079x; 1.2079x over previous
//
#include <hip/hip_runtime.h>
#include <math.h>

// Problem constants (B=2, T=8, H=W=56, C=128, heads=8, hd=16, WS=7, nh=nw=8)
constexpr int H_   = 56;
constexpr int HW_  = 56 * 56;          // 3136
constexpr int NPIX = 8 * HW_;          // 25088 (per batch)
constexpr int SLAB = 128 * HW_ * 16;   // 6422528 floats per q/k/v buffer

// ---------------------------------------------------------------------------
// GEMM: Y[M x 128] = X[M x 128] @ W[128 x 128]^T (+epilogue). Unchanged from
// round 1 (K1+K3 ~ 70us combined; attn dominates).
// ---------------------------------------------------------------------------
template <int MODE>
__global__ __launch_bounds__(256, 3) void gemm128(
    const float* X, const float* __restrict__ Wt, const float* __restrict__ bias,
    float* __restrict__ Yq, float* __restrict__ Yk, float* __restrict__ Yv,
    float* Yout)
{
  __shared__ float xT[32][132];
  __shared__ float wT[32][132];
  const int tid = threadIdx.x;
  const int tx = tid & 15, ty = tid >> 4;
  const int mbase = blockIdx.x * 128;
  const int nt = (MODE == 0) ? (int)blockIdx.y : 0;
  const float* Wp = Wt + (size_t)nt * (128 * 128);

  float acc[8][8];
#pragma unroll
  for (int i = 0; i < 8; ++i)
#pragma unroll
    for (int j = 0; j < 8; ++j) acc[i][j] = 0.f;

  const int srow = tid >> 3;
  const int scol = (tid & 7) * 4;

  for (int kt = 0; kt < 4; ++kt) {
    if (kt) __syncthreads();
#pragma unroll
    for (int p = 0; p < 4; ++p) {
      int r = p * 32 + srow;
      float4 vx = *(const float4*)&X [(size_t)(mbase + r) * 128 + kt * 32 + scol];
      float4 vw = *(const float4*)&Wp[(size_t)r * 128 + kt * 32 + scol];
      xT[scol + 0][r] = vx.x; xT[scol + 1][r] = vx.y; xT[scol + 2][r] = vx.z; xT[scol + 3][r] = vx.w;
      wT[scol + 0][r] = vw.x; wT[scol + 1][r] = vw.y; wT[scol + 2][r] = vw.z; wT[scol + 3][r] = vw.w;
    }
    __syncthreads();
#pragma unroll 4
    for (int c = 0; c < 32; ++c) {
      float4 a0 = *(const float4*)&xT[c][tx * 4];
      float4 a1 = *(const float4*)&xT[c][64 + tx * 4];
      float4 b0 = *(const float4*)&wT[c][ty * 4];
      float4 b1 = *(const float4*)&wT[c][64 + ty * 4];
      float a[8] = {a0.x, a0.y, a0.z, a0.w, a1.x, a1.y, a1.z, a1.w};
      float b[8] = {b0.x, b0.y, b0.z, b0.w, b1.x, b1.y, b1.z, b1.w};
#pragma unroll
      for (int i = 0; i < 8; ++i)
#pragma unroll
        for (int j = 0; j < 8; ++j) acc[i][j] += a[i] * b[j];
    }
  }

  if (MODE == 0) {
    const int hq = ty >> 2;
    const int cq = (ty & 3) * 4;
    float* Ybase = (nt == 0) ? Yq : ((nt == 1) ? Yk : Yv);
#pragma unroll
    for (int i = 0; i < 8; ++i) {
      int gpix = mbase + ((i < 4) ? (tx * 4 + i) : (64 + tx * 4 + (i - 4)));
      int b = gpix / NPIX;
      int rem = gpix - b * NPIX;
      int t = rem / HW_;
      int s = rem - t * HW_;
      float s0 = acc[i][0]*acc[i][0] + acc[i][1]*acc[i][1] + acc[i][2]*acc[i][2] + acc[i][3]*acc[i][3];
      float s1 = acc[i][4]*acc[i][4] + acc[i][5]*acc[i][5] + acc[i][6]*acc[i][6] + acc[i][7]*acc[i][7];
      s0 += __shfl_xor(s0, 16); s0 += __shfl_xor(s0, 32);
      s1 += __shfl_xor(s1, 16); s1 += __shfl_xor(s1, 32);
      float r0 = 1.f, r1 = 1.f;
      if (nt < 2) {
        r0 = 1.f / fmaxf(sqrtf(s0), 1e-12f);
        r1 = 1.f / fmaxf(sqrtf(s1), 1e-12f);
      }
      int bt0 = (b * 8 + hq) * 8 + t;
      int bt1 = (b * 8 + hq + 4) * 8 + t;
      float* d0 = Ybase + ((size_t)bt0 * HW_ + s) * 16 + cq;
      float* d1 = Ybase + ((size_t)bt1 * HW_ + s) * 16 + cq;
      *(float4*)d0 = make_float4(acc[i][0]*r0, acc[i][1]*r0, acc[i][2]*r0, acc[i][3]*r0);
      *(float4*)d1 = make_float4(acc[i][4]*r1, acc[i][5]*r1, acc[i][6]*r1, acc[i][7]*r1);
    }
  } else {
    float4 bb0 = *(const float4*)&bias[ty * 4];
    float4 bb1 = *(const float4*)&bias[64 + ty * 4];
#pragma unroll
    for (int i = 0; i < 8; ++i) {
      int gpix = mbase + ((i < 4) ? (tx * 4 + i) : (64 + tx * 4 + (i - 4)));
      float* dst = Yout + (size_t)gpix * 128;
      *(float4*)&dst[ty * 4]      = make_float4(acc[i][0]+bb0.x, acc[i][1]+bb0.y, acc[i][2]+bb0.z, acc[i][3]+bb0.w);
      *(float4*)&dst[64 + ty * 4] = make_float4(acc[i][4]+bb1.x, acc[i][5]+bb1.y, acc[i][6]+bb1.z, acc[i][7]+bb1.w);
    }
  }
}

// ---------------------------------------------------------------------------
// Fused window attention v2: 128 threads (2 waves) per window. The j-loop of
// both attention passes is split by parity across the two waves; wave 1 spills
// its partial (acc[16], ssum) to a small LDS buffer, wave 0 combines. The
// appearance-pass reduction buffer aliases cw[] (dead after the motion pass),
// keeping LDS at 19.8 KB -> 8 blocks/CU = 16 waves/CU (vs 9 waves/CU before).
// __launch_bounds__(128,4) pins VGPR<=128 so the register file sustains
// 4 waves/SIMD. Softmax shift via Cauchy-Schwarz bound (exact, round-1).
// ---------------------------------------------------------------------------
__global__ __launch_bounds__(128, 4) void attn_win(
    const float* __restrict__ qn, const float* __restrict__ kn, const float* __restrict__ vv,
    const float* __restrict__ pos1, const float* __restrict__ pos2,
    float* __restrict__ mid)
{
  __shared__ float cw[49][52];      // corr + pos1 (10192 B); reused as red_a
  __shared__ float qp[49][16];      // q window, later qw = qp + pos2 (3136 B)
  __shared__ float vs_[49][16];     // v window (3136 B)
  __shared__ float red_m[17 * 49];  // wave-1 motion partials (3332 B)
  float* red_a = &cw[0][0];         // wave-1 appearance partials (aliases cw)

  const int tid  = threadIdx.x;
  const int wave = tid >> 6;
  const int lane = tid & 63;
  const int gwin = blockIdx.x;
  const int bt = gwin >> 6;
  const int wy = (gwin >> 3) & 7;
  const int wx = gwin & 7;
  const int t = bt & 7;
  const int btk = bt - t + ((t < 7) ? (t + 1) : 7);   // k shifted one frame fwd
  const float* qb = qn + (size_t)bt  * (HW_ * 16);
  const float* kb = kn + (size_t)btk * (HW_ * 16);
  const float* vb = vv + (size_t)bt  * (HW_ * 16);

  // P0: load q window and v window (49 x 16 each)
  for (int f = tid; f < 196; f += 128) {
    int i = f >> 2, c4 = (f & 3) * 4;
    int hh = (i / 7) * 8 + wy, ww = (i % 7) * 8 + wx;
    size_t off = (size_t)(hh * 56 + ww) * 16 + c4;
    *(float4*)&qp[i][c4]  = *(const float4*)&qb[off];
    *(float4*)&vs_[i][c4] = *(const float4*)&vb[off];
  }
  __syncthreads();

  // P1: correlation (49 pixels x 49 displacements) + pos1
  for (int e = tid; e < 2401; e += 128) {
    int i = e / 49;
    int d = e - i * 49;
    int du = d / 7, dv = d - du * 7;
    int hh = (i / 7) * 8 + wy + du - 3;
    int ww = (i % 7) * 8 + wx + dv - 3;
    float val = 0.f;
    if ((unsigned)hh < 56u && (unsigned)ww < 56u) {
      const float4* kv = (const float4*)&kb[(size_t)(hh * 56 + ww) * 16];
      float4 k0 = kv[0], k1 = kv[1], k2 = kv[2], k3 = kv[3];
      const float* q = qp[i];
      val = q[0]*k0.x + q[1]*k0.y + q[2]*k0.z + q[3]*k0.w
          + q[4]*k1.x + q[5]*k1.y + q[6]*k1.z + q[7]*k1.w
          + q[8]*k2.x + q[9]*k2.y + q[10]*k2.z + q[11]*k2.w
          + q[12]*k3.x + q[13]*k3.y + q[14]*k3.z + q[15]*k3.w;
    }
    cw[i][d] = val + pos1[e];
  }
  if (tid < 49) { cw[tid][49] = 0.f; cw[tid][50] = 0.f; cw[tid][51] = 0.f; }
  __syncthreads();

  // qw = qp + pos2 (in place; P1 done, motion pass doesn't read qp)
  for (int f = tid; f < 196; f += 128) {
    int i = f >> 2, c4 = (f & 3) * 4;
    float4 cur = *(const float4*)&qp[i][c4];
    float4 p2  = *(const float4*)&pos2[i * 16 + c4];
    cur.x += p2.x; cur.y += p2.y; cur.z += p2.z; cur.w += p2.w;
    *(float4*)&qp[i][c4] = cur;
  }

  const int il = (lane < 49) ? lane : 48;  // lanes 49..63 shadow row 48

  // ---- motion attention (j split by wave parity) ----
  float4 cr[13];
#pragma unroll
  for (int d4 = 0; d4 < 13; ++d4) cr[d4] = *(const float4*)&cw[il][d4 * 4];
  float dii = 0.f;
#pragma unroll
  for (int d4 = 0; d4 < 13; ++d4)
    dii += cr[d4].x*cr[d4].x + cr[d4].y*cr[d4].y + cr[d4].z*cr[d4].z + cr[d4].w*cr[d4].w;
  float md = dii;
#pragma unroll
  for (int o = 32; o >= 1; o >>= 1) md = fmaxf(md, __shfl_xor(md, o));
  const float mi = sqrtf(dii * md);

  float ssum = 0.f;
  float acc[16];
#pragma unroll
  for (int c = 0; c < 16; ++c) acc[c] = 0.f;
#pragma unroll 2
  for (int j = wave; j < 49; j += 2) {
    float d0 = 0.f, d1 = 0.f, d2 = 0.f, d3 = 0.f;
#pragma unroll
    for (int d4 = 0; d4 < 13; ++d4) {
      float4 b4 = *(const float4*)&cw[j][d4 * 4];   // uniform addr -> broadcast
      d0 += cr[d4].x * b4.x; d1 += cr[d4].y * b4.y;
      d2 += cr[d4].z * b4.z; d3 += cr[d4].w * b4.w;
    }
    float p = __expf((d0 + d1) + (d2 + d3) - mi);
    ssum += p;
    const float4* vr = (const float4*)&vs_[j][0];
    float4 v0 = vr[0], v1 = vr[1], v2 = vr[2], v3 = vr[3];
    acc[0]  += p*v0.x; acc[1]  += p*v0.y; acc[2]  += p*v0.z; acc[3]  += p*v0.w;
    acc[4]  += p*v1.x; acc[5]  += p*v1.y; acc[6]  += p*v1.z; acc[7]  += p*v1.w;
    acc[8]  += p*v2.x; acc[9]  += p*v2.y; acc[10] += p*v2.z; acc[11] += p*v2.w;
    acc[12] += p*v3.x; acc[13] += p*v3.y; acc[14] += p*v3.z; acc[15] += p*v3.w;
  }
  if (wave == 1 && lane < 49) {
#pragma unroll
    for (int c = 0; c < 16; ++c) red_m[c * 49 + il] = acc[c];
    red_m[16 * 49 + il] = ssum;
  }
  __syncthreads();   // (A) motion partials + qw update visible; cw now dead

  float mo[16];
  if (wave == 0) {
    float st = ssum + red_m[16 * 49 + il];
    float inv = 0.5f / st;
#pragma unroll
    for (int c = 0; c < 16; ++c) mo[c] = (acc[c] + red_m[c * 49 + il]) * inv;
  }

  // ---- appearance attention (j split by wave parity) ----
  float4 qa0 = *(const float4*)&qp[il][0];
  float4 qa1 = *(const float4*)&qp[il][4];
  float4 qa2 = *(const float4*)&qp[il][8];
  float4 qa3 = *(const float4*)&qp[il][12];
  float dia = qa0.x*qa0.x+qa0.y*qa0.y+qa0.z*qa0.z+qa0.w*qa0.w
            + qa1.x*qa1.x+qa1.y*qa1.y+qa1.z*qa1.z+qa1.w*qa1.w
            + qa2.x*qa2.x+qa2.y*qa2.y+qa2.z*qa2.z+qa2.w*qa2.w
            + qa3.x*qa3.x+qa3.y*qa3.y+qa3.z*qa3.z+qa3.w*qa3.w;
  float mda = dia;
#pragma unroll
  for (int o = 32; o >= 1; o >>= 1) mda = fmaxf(mda, __shfl_xor(mda, o));
  const float ma = sqrtf(dia * mda);

  float ssa = 0.f;
  float aca[16];
#pragma unroll
  for (int c = 0; c < 16; ++c) aca[c] = 0.f;
#pragma unroll 2
  for (int j = wave; j < 49; j += 2) {
    const float4* qr = (const float4*)&qp[j][0];
    float4 b0 = qr[0], b1 = qr[1], b2 = qr[2], b3 = qr[3];
    float l = qa0.x*b0.x + qa0.y*b0.y + qa0.z*b0.z + qa0.w*b0.w
            + qa1.x*b1.x + qa1.y*b1.y + qa1.z*b1.z + qa1.w*b1.w
            + qa2.x*b2.x + qa2.y*b2.y + qa2.z*b2.z + qa2.w*b2.w
            + qa3.x*b3.x + qa3.y*b3.y + qa3.z*b3.z + qa3.w*b3.w;
    float p = __expf(l - ma);
    ssa += p;
    const float4* vr = (const float4*)&vs_[j][0];
    float4 v0 = vr[0], v1 = vr[1], v2 = vr[2], v3 = vr[3];
    aca[0]  += p*v0.x; aca[1]  += p*v0.y; aca[2]  += p*v0.z; aca[3]  += p*v0.w;
    aca[4]  += p*v1.x; aca[5]  += p*v1.y; aca[6]  += p*v1.z; aca[7]  += p*v1.w;
    aca[8]  += p*v2.x; aca[9]  += p*v2.y; aca[10] += p*v2.z; aca[11] += p*v2.w;
    aca[12] += p*v3.x; aca[13] += p*v3.y; aca[14] += p*v3.z; aca[15] += p*v3.w;
  }
  if (wave == 1 && lane < 49) {
#pragma unroll
    for (int c = 0; c < 16; ++c) red_a[c * 49 + il] = aca[c];
    red_a[16 * 49 + il] = ssa;
  }
  __syncthreads();   // (B)

  if (wave == 0 && lane < 49) {
    float sa = ssa + red_a[16 * 49 + il];
    float inva = 0.5f / sa;
    int b = bt >> 6, e = (bt >> 3) & 7, tt = bt & 7;
    int hh = (il / 7) * 8 + wy, ww = (il % 7) * 8 + wx;
    float* dst = mid + ((size_t)(b * NPIX + tt * HW_ + hh * 56 + ww)) * 128 + e * 16;
    float r[16];
#pragma unroll
    for (int c = 0; c < 16; ++c) r[c] = mo[c] + (aca[c] + red_a[c * 49 + il]) * inva;
    *(float4*)&dst[0]  = make_float4(r[0],  r[1],  r[2],  r[3]);
    *(float4*)&dst[4]  = make_float4(r[4],  r[5],  r[6],  r[7]);
    *(float4*)&dst[8]  = make_float4(r[8],  r[9],  r[10], r[11]);
    *(float4*)&dst[12] = make_float4(r[12], r[13], r[14], r[15]);
  }
}

// ---------------------------------------------------------------------------
extern "C" void kernel_launch(void* const* d_in, const int* in_sizes, int n_in,
                              void* d_out, int out_size, void* d_ws, size_t ws_size,
                              hipStream_t stream) {
  (void)in_sizes; (void)n_in; (void)out_size; (void)ws_size;
  const float* x      = (const float*)d_in[0];
  const float* qkv_w  = (const float*)d_in[1];
  const float* proj_w = (const float*)d_in[2];
  const float* proj_b = (const float*)d_in[3];
  const float* pos1   = (const float*)d_in[4];
  const float* pos2   = (const float*)d_in[5];
  float* out = (float*)d_out;

  float* qn = (float*)d_ws;
  float* kc = qn + SLAB;
  float* vv = kc + SLAB;

  gemm128<0><<<dim3(392, 3), 256, 0, stream>>>(x, qkv_w, nullptr, qn, kc, vv, nullptr);
  attn_win<<<dim3(8192), 128, 0, stream>>>(qn, kc, vv, pos1, pos2, out);
  gemm128<1><<<dim3(392), 256, 0, stream>>>(out, proj_w, proj_b, nullptr, nullptr, nullptr, out);
}